// Round 1
// baseline (14780.994 us; speedup 1.0000x reference)
//
#include <hip/hip_runtime.h>
#include <stdint.h>

typedef __attribute__((ext_vector_type(4))) float f32x4;
typedef __attribute__((ext_vector_type(8))) short s16x8;
typedef __attribute__((ext_vector_type(4))) unsigned short u16x4;

#define T_SEQ 1024
#define HID 512
#define NWG1 64
#define NWG2 128
#define RS 516  // LDS row stride in floats: 516%4==0 (b128-aligned), 516%32==4 -> conflict-free banks

__device__ __forceinline__ unsigned short f2bf(float f) {
  uint32_t u = __float_as_uint(f);
  u += 0x7fffu + ((u >> 16) & 1u);  // round-to-nearest-even
  return (unsigned short)(u >> 16);
}
__device__ __forceinline__ float sigf(float x) { return 1.f / (1.f + __expf(-x)); }

#define GLL(gp, lp)                                                      \
  __builtin_amdgcn_global_load_lds(                                     \
      (const __attribute__((address_space(1))) void*)(gp),              \
      (__attribute__((address_space(3))) void*)(lp), 16, 0, 0)

// ---------------- small prep kernels ----------------
__global__ __launch_bounds__(256) void embed_kernel(const int* __restrict__ inp,
                                                    const float* __restrict__ wte,
                                                    unsigned short* __restrict__ xbf) {
  const int m = blockIdx.x;  // m = b*1024 + t
  const int idx = inp[m];
  const float* src = wte + (size_t)idx * HID;
  unsigned short* dst = xbf + (size_t)m * HID;
  const int e = threadIdx.x;
  dst[e] = f2bf(src[e]);
  dst[e + 256] = f2bf(src[e + 256]);
}

__global__ __launch_bounds__(256) void cvt_bf16_kernel(const float* __restrict__ src,
                                                       unsigned short* __restrict__ dst,
                                                       int n4) {
  const int i = blockIdx.x * 256 + threadIdx.x;
  if (i >= n4) return;
  f32x4 v = ((const f32x4*)src)[i];
  u16x4 o;
  o.x = f2bf(v.x); o.y = f2bf(v.y); o.z = f2bf(v.z); o.w = f2bf(v.w);
  ((u16x4*)dst)[i] = o;
}

__global__ __launch_bounds__(256) void bias_sum_kernel(const float* __restrict__ a,
                                                       const float* __restrict__ b,
                                                       float* __restrict__ o, int n) {
  const int i = blockIdx.x * 256 + threadIdx.x;
  if (i < n) o[i] = a[i] + b[i];
}

// ---------------- bf16 MFMA GEMM:  C[m][n] = sum_k A[m][k]*B[n][k] + bias[n] ----------------
// 128x128 tile, 4 waves (2x2 of 64x64), BK=32, global_load_lds staging.
// MODE 0: C row = m (ldc=N).  MODE 1: m = t*8+b -> C row = b*1024+t (ldc=N).
template <int MODE>
__global__ __launch_bounds__(256) void gemm_bt(const unsigned short* __restrict__ A,
                                               const unsigned short* __restrict__ B,
                                               float* __restrict__ C,
                                               const float* __restrict__ bias,
                                               int M, int N, int K) {
  __shared__ unsigned short As[128 * 32];
  __shared__ unsigned short Bs[128 * 32];
  const int nTiles = N >> 7;
  const int mt = blockIdx.x / nTiles;
  const int nt = blockIdx.x - mt * nTiles;
  const int m0 = mt << 7, n0 = nt << 7;
  const int tid = threadIdx.x;
  const int wave = tid >> 6, lane = tid & 63;
  const int wm = wave >> 1, wn = wave & 1;

  // staging chunk ids: 16B chunks, linear LDS order (HW: wave base + lane*16)
  const int c1 = wave * 64 + lane;
  const int c2 = 256 + c1;
  const unsigned short* gA1 = A + (size_t)(m0 + (c1 >> 2)) * K + (c1 & 3) * 8;
  const unsigned short* gA2 = A + (size_t)(m0 + (c2 >> 2)) * K + (c2 & 3) * 8;
  const unsigned short* gB1 = B + (size_t)(n0 + (c1 >> 2)) * K + (c1 & 3) * 8;
  const unsigned short* gB2 = B + (size_t)(n0 + (c2 >> 2)) * K + (c2 & 3) * 8;
  unsigned short* lA1 = As + wave * 512;
  unsigned short* lA2 = As + 2048 + wave * 512;
  unsigned short* lB1 = Bs + wave * 512;
  unsigned short* lB2 = Bs + 2048 + wave * 512;

  f32x4 acc[4][4] = {};
  const int row_lo = lane & 15;
  const int kq = (lane >> 4) * 8;

  for (int k0 = 0; k0 < K; k0 += 32) {
    GLL(gA1 + k0, lA1);
    GLL(gA2 + k0, lA2);
    GLL(gB1 + k0, lB1);
    GLL(gB2 + k0, lB2);
    __syncthreads();  // drains vmcnt -> LDS tile ready
    s16x8 af[4], bfr[4];
#pragma unroll
    for (int f = 0; f < 4; ++f) {
      af[f] = *(const s16x8*)(As + (wm * 64 + f * 16 + row_lo) * 32 + kq);
      bfr[f] = *(const s16x8*)(Bs + (wn * 64 + f * 16 + row_lo) * 32 + kq);
    }
#pragma unroll
    for (int i = 0; i < 4; ++i)
#pragma unroll
      for (int j = 0; j < 4; ++j)
        acc[i][j] = __builtin_amdgcn_mfma_f32_16x16x32_bf16(af[i], bfr[j], acc[i][j], 0, 0, 0);
    __syncthreads();  // all reads done before next overwrite
  }

  float bv[4];
#pragma unroll
  for (int j = 0; j < 4; ++j) bv[j] = bias[n0 + wn * 64 + j * 16 + row_lo];
  const int rbase = (lane >> 4) * 4;
#pragma unroll
  for (int i = 0; i < 4; ++i) {
#pragma unroll
    for (int r = 0; r < 4; ++r) {
      const int m = m0 + wm * 64 + i * 16 + rbase + r;
      const size_t row = MODE ? ((size_t)(m & 7) * T_SEQ + (m >> 3)) : (size_t)m;
      float* cp = C + row * (size_t)N;
#pragma unroll
      for (int j = 0; j < 4; ++j) cp[n0 + wn * 64 + j * 16 + row_lo] = acc[i][j][r] + bv[j];
    }
  }
}

// ---------------- persistent 2-layer LSTM ----------------
// 192 WGs x 256 thr, all co-resident (100KB LDS -> 1 WG/CU).
// Layer1 WGs (0..63): 8 hidden units each, gates = xg1(precomputed) + h1 @ Whh0^T.
// Layer2 WGs (64..191): 4 hidden units each, gates = h1_t @ Wih1^T + h2 @ Whh1^T + b.
// Sync: monotonic counters cnt1/cnt2 (device scope), full h history in global.
__global__ __launch_bounds__(256) void lstm_kernel(
    const float* __restrict__ xg1,    // [8192][2048], row = b*1024+t
    const float* __restrict__ Whh,    // [2][2048][512]
    const float* __restrict__ Wih,    // [2][2048][512]
    const float* __restrict__ b_ih,   // [2][2048]
    const float* __restrict__ b_hh,   // [2][2048]
    float* __restrict__ h1_all,       // [T][8][512]
    float* __restrict__ h2_all,       // [T][8][512]
    unsigned short* __restrict__ h2bf,// [T*8][512]
    int* __restrict__ cnt) {
  __shared__ float smem[32 * RS + 16 * RS + 256];  // 25024 floats = 100096 B
  float* Wl = smem;                 // 32 rows x RS
  float* HB = smem + 32 * RS;       // up to 16 rows x RS
  float* GT = smem + 48 * RS;       // 256 gate slots

  const int wg = blockIdx.x;
  const int tid = threadIdx.x;
  int* cnt1 = cnt;
  int* cnt2 = cnt + 32;

  if (wg < NWG1) {
    // ---------------- layer 1 ----------------
    const int u0 = wg * 8;
    const int g = tid >> 6, uu = (tid >> 3) & 7, b = tid & 7;  // tid = g*64+uu*8+b
    for (int idx = tid; idx < 32 * 512; idx += 256) {
      int r = idx >> 9, k = idx & 511;
      int grow = (r >> 3) * 512 + u0 + (r & 7);
      Wl[r * RS + k] = Whh[(size_t)grow * 512 + k];
    }
    const float* wrow = Wl + (g * 8 + uu) * RS;
    const float* hrow = HB + b * RS;
    const size_t xg_base = ((size_t)b * T_SEQ) * 2048 + g * 512 + u0 + uu;
    float c = 0.f;
    __syncthreads();
    for (int t = 0; t < T_SEQ; ++t) {
      float xgv = xg1[xg_base + (size_t)t * 2048];  // independent: issued before spin
      if (tid == 0 && t > 0) {
        while (__hip_atomic_load(cnt1, __ATOMIC_RELAXED, __HIP_MEMORY_SCOPE_AGENT) < NWG1 * t)
          __builtin_amdgcn_s_sleep(2);
        __threadfence();  // acquire
      }
      __syncthreads();
      if (t == 0) {
        for (int idx = tid; idx < 8 * 512; idx += 256) HB[(idx >> 9) * RS + (idx & 511)] = 0.f;
      } else {
        const float* hp = h1_all + (size_t)(t - 1) * 4096;
        for (int idx = tid; idx < 8 * 512; idx += 256) HB[(idx >> 9) * RS + (idx & 511)] = hp[idx];
      }
      __syncthreads();
      float acc = xgv;
      const f32x4* wp = (const f32x4*)wrow;
      const f32x4* hp4 = (const f32x4*)hrow;
#pragma unroll 8
      for (int kk = 0; kk < 128; ++kk) {
        f32x4 w = wp[kk], h = hp4[kk];
        acc = fmaf(w.x, h.x, acc); acc = fmaf(w.y, h.y, acc);
        acc = fmaf(w.z, h.z, acc); acc = fmaf(w.w, h.w, acc);
      }
      GT[tid] = acc;
      __syncthreads();
      if (tid < 64) {  // wave 0 does the pointwise update
        float iv = GT[tid], fv = GT[64 + tid], gv = GT[128 + tid], ov = GT[192 + tid];
        c = sigf(fv) * c + sigf(iv) * tanhf(gv);
        float hv = sigf(ov) * tanhf(c);
        h1_all[(size_t)t * 4096 + (tid & 7) * 512 + u0 + (tid >> 3)] = hv;
        __threadfence();  // release
        if (tid == 0) atomicAdd(cnt1, 1);
      }
    }
  } else {
    // ---------------- layer 2 ----------------
    const int u0 = (wg - NWG1) * 4;
    const int g = tid >> 6, mat = tid & 1, q = (tid >> 1) & 31;  // tid = g*64+q*2+mat
    const int uu = q >> 3, b = q & 7;
    const float* Wi2 = Wih + (size_t)2048 * 512;
    const float* Wh2 = Whh + (size_t)2048 * 512;
    for (int idx = tid; idx < 16 * 512; idx += 256) {
      int r = idx >> 9, k = idx & 511;
      int grow = (r >> 2) * 512 + u0 + (r & 3);
      Wl[r * RS + k] = Wi2[(size_t)grow * 512 + k];
      Wl[(16 + r) * RS + k] = Wh2[(size_t)grow * 512 + k];
    }
    const float* wrow = Wl + ((mat ? 16 : 0) + g * 4 + uu) * RS;
    const float* hrow = HB + (mat ? 8 : 0) * RS + b * RS;
    float bv = 0.f;
    if (mat == 0) {
      int grow = g * 512 + u0 + uu;
      bv = b_ih[2048 + grow] + b_hh[2048 + grow];
    }
    float c = 0.f;
    __syncthreads();
    for (int t = 0; t < T_SEQ; ++t) {
      if (tid == 0) {
        while (__hip_atomic_load(cnt1, __ATOMIC_RELAXED, __HIP_MEMORY_SCOPE_AGENT) < NWG1 * (t + 1))
          __builtin_amdgcn_s_sleep(2);
        if (t > 0)
          while (__hip_atomic_load(cnt2, __ATOMIC_RELAXED, __HIP_MEMORY_SCOPE_AGENT) < NWG2 * t)
            __builtin_amdgcn_s_sleep(2);
        __threadfence();  // acquire
      }
      __syncthreads();
      {
        const float* h1p = h1_all + (size_t)t * 4096;
        for (int idx = tid; idx < 8 * 512; idx += 256)
          HB[(idx >> 9) * RS + (idx & 511)] = h1p[idx];
        if (t == 0) {
          for (int idx = tid; idx < 8 * 512; idx += 256)
            HB[8 * RS + (idx >> 9) * RS + (idx & 511)] = 0.f;
        } else {
          const float* h2p = h2_all + (size_t)(t - 1) * 4096;
          for (int idx = tid; idx < 8 * 512; idx += 256)
            HB[8 * RS + (idx >> 9) * RS + (idx & 511)] = h2p[idx];
        }
      }
      __syncthreads();
      float acc = bv;
      const f32x4* wp = (const f32x4*)wrow;
      const f32x4* hp4 = (const f32x4*)hrow;
#pragma unroll 8
      for (int kk = 0; kk < 128; ++kk) {
        f32x4 w = wp[kk], h = hp4[kk];
        acc = fmaf(w.x, h.x, acc); acc = fmaf(w.y, h.y, acc);
        acc = fmaf(w.z, h.z, acc); acc = fmaf(w.w, h.w, acc);
      }
      acc += __shfl_xor(acc, 1);  // combine ih-part + hh-part
      if (mat == 0) GT[g * 32 + q] = acc;
      __syncthreads();
      if (tid < 32) {
        float iv = GT[tid], fv = GT[32 + tid], gv = GT[64 + tid], ov = GT[96 + tid];
        c = sigf(fv) * c + sigf(iv) * tanhf(gv);
        float hv = sigf(ov) * tanhf(c);
        int uo = u0 + (tid >> 3), bb = tid & 7;
        h2_all[(size_t)t * 4096 + bb * 512 + uo] = hv;
        h2bf[((size_t)t * 8 + bb) * 512 + uo] = f2bf(hv);
        __threadfence();  // release
        if (tid == 0) atomicAdd(cnt2, 1);
      }
    }
  }
}

// ---------------- host launch ----------------
extern "C" void kernel_launch(void* const* d_in, const int* in_sizes, int n_in,
                              void* d_out, int out_size, void* d_ws, size_t ws_size,
                              hipStream_t stream) {
  (void)in_sizes; (void)n_in; (void)out_size; (void)ws_size;
  const int* inp = (const int*)d_in[0];
  const float* wte = (const float*)d_in[1];
  const float* W_ih = (const float*)d_in[2];
  const float* W_hh = (const float*)d_in[3];
  const float* b_ih = (const float*)d_in[4];
  const float* b_hh = (const float*)d_in[5];
  const float* fc_w = (const float*)d_in[6];
  const float* fc_b = (const float*)d_in[7];
  float* out = (float*)d_out;

  // Large intermediates live INSIDE d_out (1 GB, fully overwritten by final FC GEMM).
  char* ob = (char*)d_out;
  float* xg1 = (float*)(ob);                                   // 64 MiB
  float* h1_all = (float*)(ob + (64u << 20));                  // 16 MiB
  float* h2_all = (float*)(ob + (80u << 20));                  // 16 MiB
  unsigned short* x_bf = (unsigned short*)(ob + (96u << 20));  //  8 MiB

  char* ws = (char*)d_ws;                                      // needs ~43 MiB
  unsigned short* wih0_bf = (unsigned short*)(ws);             //  2 MiB
  unsigned short* fcw_bf = (unsigned short*)(ws + (2u << 20)); // 31.25 MiB
  float* bias12 = (float*)(ws + (34u << 20));                  //  8 KiB
  unsigned short* h2bf = (unsigned short*)(ws + (35u << 20));  //  8 MiB
  int* cnt = (int*)(ws + (43u << 20));                         //  256 B

  hipMemsetAsync(cnt, 0, 256, stream);  // reset spin counters every call (graph-safe)
  embed_kernel<<<8192, 256, 0, stream>>>(inp, wte, x_bf);
  cvt_bf16_kernel<<<1024, 256, 0, stream>>>(W_ih, wih0_bf, 2048 * 512 / 4);
  cvt_bf16_kernel<<<16000, 256, 0, stream>>>(fc_w, fcw_bf, 32000 * 512 / 4);
  bias_sum_kernel<<<8, 256, 0, stream>>>(b_ih, b_hh, bias12, 2048);
  // xg1 = x @ W_ih0^T + (b_ih0 + b_hh0)   [8192 x 2048]
  gemm_bt<0><<<64 * 16, 256, 0, stream>>>(x_bf, wih0_bf, xg1, bias12, 8192, 2048, 512);
  lstm_kernel<<<NWG1 + NWG2, 256, 0, stream>>>(xg1, W_hh, W_ih, b_ih, b_hh,
                                               h1_all, h2_all, h2bf, cnt);
  // logits = h2 @ fc_w^T + fc_b   [8192 x 32000], rows remapped t*8+b -> b*1024+t
  gemm_bt<1><<<64 * 250, 256, 0, stream>>>(h2bf, fcw_bf, out, fc_b, 8192, 32000, 512);
}

// Round 2
// 5762.931 us; speedup vs baseline: 2.5648x; 2.5648x over previous
//
#include <hip/hip_runtime.h>
#include <stdint.h>

typedef __attribute__((ext_vector_type(4))) float f32x4;
typedef __attribute__((ext_vector_type(8))) short s16x8;
typedef __attribute__((ext_vector_type(4))) unsigned short u16x4;

#define T_SEQ 1024
#define HID 512
#define SU 516  // HBL row stride in u32: 516*4 % 128 == 16 -> rows offset 4 banks

__device__ __forceinline__ unsigned short f2bf(float f) {
  uint32_t u = __float_as_uint(f);
  u += 0x7fffu + ((u >> 16) & 1u);  // round-to-nearest-even
  return (unsigned short)(u >> 16);
}
__device__ __forceinline__ float sigf(float x) { return 1.f / (1.f + __expf(-x)); }
__device__ __forceinline__ float tanhfast(float x) {
  float e = __expf(2.f * x);
  return (e - 1.f) / (e + 1.f);
}

#define ALOAD(p) __hip_atomic_load((p), __ATOMIC_RELAXED, __HIP_MEMORY_SCOPE_AGENT)
#define ASTORE(p, v) __hip_atomic_store((p), (v), __ATOMIC_RELAXED, __HIP_MEMORY_SCOPE_AGENT)

#define GLL(gp, lp)                                                      \
  __builtin_amdgcn_global_load_lds(                                     \
      (const __attribute__((address_space(1))) void*)(gp),              \
      (__attribute__((address_space(3))) void*)(lp), 16, 0, 0)

// ---------------- small prep kernels ----------------
__global__ __launch_bounds__(256) void embed_kernel(const int* __restrict__ inp,
                                                    const float* __restrict__ wte,
                                                    unsigned short* __restrict__ xbf) {
  const int m = blockIdx.x;  // m = b*1024 + t
  const int idx = inp[m];
  const float* src = wte + (size_t)idx * HID;
  unsigned short* dst = xbf + (size_t)m * HID;
  const int e = threadIdx.x;
  dst[e] = f2bf(src[e]);
  dst[e + 256] = f2bf(src[e + 256]);
}

__global__ __launch_bounds__(256) void cvt_bf16_kernel(const float* __restrict__ src,
                                                       unsigned short* __restrict__ dst,
                                                       int n4) {
  const int i = blockIdx.x * 256 + threadIdx.x;
  if (i >= n4) return;
  f32x4 v = ((const f32x4*)src)[i];
  u16x4 o;
  o.x = f2bf(v.x); o.y = f2bf(v.y); o.z = f2bf(v.z); o.w = f2bf(v.w);
  ((u16x4*)dst)[i] = o;
}

__global__ __launch_bounds__(256) void bias_sum_kernel(const float* __restrict__ a,
                                                       const float* __restrict__ b,
                                                       float* __restrict__ o, int n) {
  const int i = blockIdx.x * 256 + threadIdx.x;
  if (i < n) o[i] = a[i] + b[i];
}

// ---------------- bf16 MFMA GEMM:  C[m][n] = sum_k A[m][k]*B[n][k] + bias[n] ----------------
// MODE 0: C row = m. MODE 1: m = t*8+b -> C row = b*1024+t. MODE 2: m = b*1024+t -> C row = t*8+b.
template <int MODE>
__global__ __launch_bounds__(256) void gemm_bt(const unsigned short* __restrict__ A,
                                               const unsigned short* __restrict__ B,
                                               float* __restrict__ C,
                                               const float* __restrict__ bias,
                                               int M, int N, int K) {
  __shared__ unsigned short As[128 * 32];
  __shared__ unsigned short Bs[128 * 32];
  const int nTiles = N >> 7;
  const int mt = blockIdx.x / nTiles;
  const int nt = blockIdx.x - mt * nTiles;
  const int m0 = mt << 7, n0 = nt << 7;
  const int tid = threadIdx.x;
  const int wave = tid >> 6, lane = tid & 63;
  const int wm = wave >> 1, wn = wave & 1;

  const int c1 = wave * 64 + lane;
  const int c2 = 256 + c1;
  const unsigned short* gA1 = A + (size_t)(m0 + (c1 >> 2)) * K + (c1 & 3) * 8;
  const unsigned short* gA2 = A + (size_t)(m0 + (c2 >> 2)) * K + (c2 & 3) * 8;
  const unsigned short* gB1 = B + (size_t)(n0 + (c1 >> 2)) * K + (c1 & 3) * 8;
  const unsigned short* gB2 = B + (size_t)(n0 + (c2 >> 2)) * K + (c2 & 3) * 8;
  unsigned short* lA1 = As + wave * 512;
  unsigned short* lA2 = As + 2048 + wave * 512;
  unsigned short* lB1 = Bs + wave * 512;
  unsigned short* lB2 = Bs + 2048 + wave * 512;

  f32x4 acc[4][4] = {};
  const int row_lo = lane & 15;
  const int kq = (lane >> 4) * 8;

  for (int k0 = 0; k0 < K; k0 += 32) {
    GLL(gA1 + k0, lA1);
    GLL(gA2 + k0, lA2);
    GLL(gB1 + k0, lB1);
    GLL(gB2 + k0, lB2);
    __syncthreads();
    s16x8 af[4], bfr[4];
#pragma unroll
    for (int f = 0; f < 4; ++f) {
      af[f] = *(const s16x8*)(As + (wm * 64 + f * 16 + row_lo) * 32 + kq);
      bfr[f] = *(const s16x8*)(Bs + (wn * 64 + f * 16 + row_lo) * 32 + kq);
    }
#pragma unroll
    for (int i = 0; i < 4; ++i)
#pragma unroll
      for (int j = 0; j < 4; ++j)
        acc[i][j] = __builtin_amdgcn_mfma_f32_16x16x32_bf16(af[i], bfr[j], acc[i][j], 0, 0, 0);
    __syncthreads();
  }

  float bv[4];
#pragma unroll
  for (int j = 0; j < 4; ++j) bv[j] = bias[n0 + wn * 64 + j * 16 + row_lo];
  const int rbase = (lane >> 4) * 4;
#pragma unroll
  for (int i = 0; i < 4; ++i) {
#pragma unroll
    for (int r = 0; r < 4; ++r) {
      const int m = m0 + wm * 64 + i * 16 + rbase + r;
      const size_t row = MODE == 1 ? ((size_t)(m & 7) * T_SEQ + (m >> 3))
                       : MODE == 2 ? ((size_t)(m & (T_SEQ - 1)) * 8 + (m >> 10))
                                   : (size_t)m;
      float* cp = C + row * (size_t)N;
#pragma unroll
      for (int j = 0; j < 4; ++j) cp[n0 + wn * 64 + j * 16 + row_lo] = acc[i][j][r] + bv[j];
    }
  }
}

// ---------------- persistent 2-layer LSTM (MFMA recurrence, fence-free MALL sync) ----------------
// 128 WGs x 256 thr. WGs 0..63: layer 1 (8 units each); 64..127: layer 2 (8 units each).
// Weights live in VGPRs as MFMA B-fragments. h exchanged as packed-bf16 relaxed agent atomics.
template <bool IS_L1, int KTW>
__device__ __forceinline__ void lstm_body(
    int u0, int tid,
    const float* __restrict__ xg1t,           // [t*8+b][2048] (L1 only)
    const unsigned short* __restrict__ Wa,    // L1: whh_l1 ; L2: wih_l2
    const unsigned short* __restrict__ Wb,    // L1: unused ; L2: whh_l2
    const float* __restrict__ b_ih, const float* __restrict__ b_hh,
    unsigned int* __restrict__ h1bf, unsigned int* __restrict__ h2bf,
    int* cnt1, int* cnt2,
    unsigned int* HBLu, f32x4* CLred, float* CP, float* XG) {
  const int wave = tid >> 6, lane = tid & 63;
  const int nt = wave & 1, kh = wave >> 1;
  const int col = lane & 15, grp = lane >> 4;

  // ---- B-fragments (weights) in registers, loaded once ----
  const int wrow = nt * 16 + col;                    // WG-local gate row 0..31 (g-major, 8 units)
  const int grow = (wrow >> 3) * 512 + u0 + (wrow & 7);  // global gate row
  s16x8 bfrag[KTW];
#pragma unroll
  for (int f = 0; f < KTW; ++f) {
    const int kt = kh * KTW + f;
    const unsigned short* W = (IS_L1 || kt < 16) ? Wa : Wb;
    const int kk = (IS_L1 ? kt : (kt & 15)) * 32;
    bfrag[f] = *(const s16x8*)(W + (size_t)grow * 512 + kk + grp * 8);
  }

  // ---- pointwise state (wave 0): lane = b*8 + uu ----
  const int pb = lane >> 3, puu = lane & 7;
  float cst = 0.f;
  float bias_g[4] = {0.f, 0.f, 0.f, 0.f};
  if (!IS_L1 && wave == 0) {
#pragma unroll
    for (int g = 0; g < 4; ++g) {
      const int gr = 2048 + g * 512 + u0 + puu;
      bias_g[g] = b_ih[gr] + b_hh[gr];
    }
  }

  const unsigned short* hb = (const unsigned short*)HBLu;  // row stride SU*2 ushorts
  const int arow = lane & 7;

  for (int t = 0; t < T_SEQ; ++t) {
    // ---- wait for producers (relaxed polls to the coherence point) ----
    if (tid == 0) {
      if (IS_L1) {
        if (t > 0)
          while (ALOAD(cnt1) < 64 * t) __builtin_amdgcn_s_sleep(1);
      } else {
        while (ALOAD(cnt1) < 64 * (t + 1)) __builtin_amdgcn_s_sleep(1);
        if (t > 0)
          while (ALOAD(cnt2) < 64 * t) __builtin_amdgcn_s_sleep(1);
      }
    }
    __syncthreads();

    // ---- stage h (and xg) into LDS ----
#pragma unroll
    for (int i = 0; i < 8; ++i) {
      const int d = tid + 256 * i;
      const int row = d >> 8, c8 = d & 255;
      if (IS_L1) {
        unsigned int v = 0;
        if (t > 0) v = ALOAD(h1bf + (size_t)(t - 1) * 2048 + row * 256 + c8);
        HBLu[row * SU + c8] = v;
      } else {
        HBLu[row * SU + c8] = ALOAD(h1bf + (size_t)t * 2048 + row * 256 + c8);
        unsigned int v2 = 0;
        if (t > 0) v2 = ALOAD(h2bf + (size_t)(t - 1) * 2048 + row * 256 + c8);
        HBLu[row * SU + 256 + c8] = v2;
      }
    }
    if (IS_L1)
      XG[tid] = xg1t[(size_t)(t * 8 + (tid >> 5)) * 2048 + ((tid >> 3) & 3) * 512 + u0 + (tid & 7)];
    __syncthreads();

    // ---- MFMA: C[16b x 16n] over this wave's k-half ----
    f32x4 aA = {}, aB = {};
#pragma unroll
    for (int f = 0; f < KTW; f += 2) {
      const int kt0 = kh * KTW + f;
      s16x8 a0 = *(const s16x8*)(hb + arow * (SU * 2) + kt0 * 32 + grp * 8);
      s16x8 a1 = *(const s16x8*)(hb + arow * (SU * 2) + (kt0 + 1) * 32 + grp * 8);
      aA = __builtin_amdgcn_mfma_f32_16x16x32_bf16(a0, bfrag[f], aA, 0, 0, 0);
      aB = __builtin_amdgcn_mfma_f32_16x16x32_bf16(a1, bfrag[f + 1], aB, 0, 0, 0);
    }
    f32x4 acc = aA + aB;

    // ---- cross-wave k-reduce + gate exchange ----
    if (kh == 1) CLred[nt * 64 + lane] = acc;
    __syncthreads();
    if (kh == 0) {
      acc += CLred[nt * 64 + lane];
      if (grp < 2) {  // C rows 0..7 are real batches
#pragma unroll
        for (int q = 0; q < 4; ++q) CP[nt * 128 + col * 8 + (grp * 4 + q)] = acc[q];
      }
    }
    __syncthreads();

    // ---- pointwise (wave 0), h store, counter release ----
    if (wave == 0) {
      float gi = CP[puu * 8 + pb];
      float gf = CP[(8 + puu) * 8 + pb];
      float gg = CP[128 + puu * 8 + pb];
      float go = CP[128 + (8 + puu) * 8 + pb];
      if (IS_L1) {
        gi += XG[pb * 32 + puu];       gf += XG[pb * 32 + 8 + puu];
        gg += XG[pb * 32 + 16 + puu];  go += XG[pb * 32 + 24 + puu];
      } else {
        gi += bias_g[0]; gf += bias_g[1]; gg += bias_g[2]; go += bias_g[3];
      }
      cst = sigf(gf) * cst + sigf(gi) * tanhfast(gg);
      const float hv = sigf(go) * tanhfast(cst);
      const unsigned int hb16 = f2bf(hv);
      const unsigned int partner = (unsigned int)__shfl_xor((int)hb16, 1);
      if ((puu & 1) == 0) {
        unsigned int pack = (hb16 & 0xffffu) | (partner << 16);
        unsigned int* dst = (IS_L1 ? h1bf : h2bf) + (size_t)(t * 8 + pb) * 256 + ((u0 + puu) >> 1);
        ASTORE(dst, pack);
      }
      asm volatile("s_waitcnt vmcnt(0)" ::: "memory");
      if (lane == 0)
        __hip_atomic_fetch_add(IS_L1 ? cnt1 : cnt2, 1, __ATOMIC_RELAXED, __HIP_MEMORY_SCOPE_AGENT);
    }
  }
}

__global__ __launch_bounds__(256) void lstm_kernel(
    const float* __restrict__ xg1t,
    const unsigned short* __restrict__ wihbf,   // [2][2048][512] bf16
    const unsigned short* __restrict__ whhbf,   // [2][2048][512] bf16
    const float* __restrict__ b_ih, const float* __restrict__ b_hh,
    unsigned int* __restrict__ h1bf, unsigned int* __restrict__ h2bf,
    int* __restrict__ cnt) {
  __shared__ unsigned int HBLu[8 * SU];   // 16.5 KB
  __shared__ f32x4 CLred[128];            // 2 KB
  __shared__ float CP[256];
  __shared__ float XG[256];
  const int wg = blockIdx.x, tid = threadIdx.x;
  if (wg < 64)
    lstm_body<true, 8>(wg * 8, tid, xg1t, whhbf, nullptr, b_ih, b_hh,
                       h1bf, h2bf, cnt, cnt + 64, HBLu, CLred, CP, XG);
  else
    lstm_body<false, 16>((wg - 64) * 8, tid, xg1t,
                         wihbf + (size_t)2048 * 512, whhbf + (size_t)2048 * 512,
                         b_ih, b_hh, h1bf, h2bf, cnt, cnt + 64, HBLu, CLred, CP, XG);
}

// ---------------- host launch ----------------
extern "C" void kernel_launch(void* const* d_in, const int* in_sizes, int n_in,
                              void* d_out, int out_size, void* d_ws, size_t ws_size,
                              hipStream_t stream) {
  (void)in_sizes; (void)n_in; (void)out_size; (void)ws_size;
  const int* inp = (const int*)d_in[0];
  const float* wte = (const float*)d_in[1];
  const float* W_ih = (const float*)d_in[2];
  const float* W_hh = (const float*)d_in[3];
  const float* b_ih = (const float*)d_in[4];
  const float* b_hh = (const float*)d_in[5];
  const float* fc_w = (const float*)d_in[6];
  const float* fc_b = (const float*)d_in[7];
  float* out = (float*)d_out;

  // Large intermediates inside d_out (1 GB; fully overwritten by final FC GEMM afterwards).
  char* ob = (char*)d_out;
  float* xg1t = (float*)(ob);                                    // 64 MiB  [t*8+b][2048]
  unsigned int* h1bf = (unsigned int*)(ob + (64u << 20));        //  8 MiB  [t*8+b][256] packed bf16
  unsigned short* whh_bf = (unsigned short*)(ob + (72u << 20));  //  4 MiB
  unsigned short* wih_bf = (unsigned short*)(ob + (76u << 20));  //  4 MiB
  unsigned short* x_bf = (unsigned short*)(ob + (80u << 20));    //  8 MiB

  char* ws = (char*)d_ws;  // footprint kept within round-1-proven 43 MiB
  unsigned short* fcw_bf = (unsigned short*)(ws);                //  31.25 MiB
  float* bias12 = (float*)(ws + (32u << 20));                    //  8 KiB
  int* cnt = (int*)(ws + (33u << 20));                           //  512 B
  unsigned int* h2bf = (unsigned int*)(ws + (35u << 20));        //  8 MiB [t*8+b][256]

  hipMemsetAsync(cnt, 0, 512, stream);
  embed_kernel<<<8192, 256, 0, stream>>>(inp, wte, x_bf);
  cvt_bf16_kernel<<<2048, 256, 0, stream>>>(W_ih, wih_bf, 2 * 2048 * 512 / 4);
  cvt_bf16_kernel<<<2048, 256, 0, stream>>>(W_hh, whh_bf, 2 * 2048 * 512 / 4);
  cvt_bf16_kernel<<<16000, 256, 0, stream>>>(fc_w, fcw_bf, 32000 * 512 / 4);
  bias_sum_kernel<<<8, 256, 0, stream>>>(b_ih, b_hh, bias12, 2048);
  // xg1t[t*8+b][g] = x @ W_ih0^T + (b_ih0 + b_hh0)
  gemm_bt<2><<<64 * 16, 256, 0, stream>>>(x_bf, wih_bf, xg1t, bias12, 8192, 2048, 512);
  lstm_kernel<<<128, 256, 0, stream>>>(xg1t, wih_bf, whh_bf, b_ih, b_hh, h1bf, h2bf, cnt);
  // logits = h2 @ fc_w^T + fc_b  (A rows t*8+b -> C rows b*1024+t)
  gemm_bt<1><<<64 * 250, 256, 0, stream>>>((const unsigned short*)h2bf, fcw_bf, out, fc_b,
                                           8192, 32000, 512);
}